// Round 3
// baseline (323.526 us; speedup 1.0000x reference)
//
#include <hip/hip_runtime.h>
#include <hip/hip_bf16.h>

#define S_ 64
#define P_ 32
#define N_ 2048
#define H_ 64
#define E_ 64
#define D1_ 512
#define D2_ 1024
#define EPS_ 1e-5f

typedef unsigned short u16;
using bf16x8 = __attribute__((ext_vector_type(8))) __bf16;
using floatx4 = __attribute__((ext_vector_type(4))) float;

__device__ inline u16 f2bf(float x) {
    unsigned u = __float_as_uint(x);
    unsigned r = (u + 0x7fffu + ((u >> 16) & 1u)) >> 16;
    return (u16)r;
}

// build a bf16x8 fragment = bf16(relu(a - b)) from two float4 pairs
__device__ inline bf16x8 frag_relu_diff(const float4& alo, const float4& ahi,
                                        const float4& blo, const float4& bhi) {
    bf16x8 r;
    r[0] = (__bf16)fmaxf(alo.x - blo.x, 0.f);
    r[1] = (__bf16)fmaxf(alo.y - blo.y, 0.f);
    r[2] = (__bf16)fmaxf(alo.z - blo.z, 0.f);
    r[3] = (__bf16)fmaxf(alo.w - blo.w, 0.f);
    r[4] = (__bf16)fmaxf(ahi.x - bhi.x, 0.f);
    r[5] = (__bf16)fmaxf(ahi.y - bhi.y, 0.f);
    r[6] = (__bf16)fmaxf(ahi.z - bhi.z, 0.f);
    r[7] = (__bf16)fmaxf(ahi.w - bhi.w, 0.f);
    return r;
}

// ---- fused prep: blocks 0..63 -> per-scene Weq+wu+BN1; blocks 64..191 -> W2 transpose ----
// A[n,d] = (w[n,d]-mean_w)*sc+be1 ; B[n,d] = (u[n,d]-mean_u)*sc   (per scene, per d)
__global__ __launch_bounds__(512)
void k_prep(const float* __restrict__ pos, const float* __restrict__ h,
            const float* __restrict__ We, const float* __restrict__ W1,
            const float* __restrict__ g1, const float* __restrict__ be1,
            const float* __restrict__ W2,
            float* __restrict__ A, float* __restrict__ Bv, u16* __restrict__ w2t) {
    __shared__ float smem[64 * 65];
    const int bid = blockIdx.x;
    const int tid = threadIdx.x;
    if (bid < S_) {
        const int s = bid;
        const int d = tid;  // 512 threads = 512 channels
        float* hs = smem;          // 2048 f32: h[j][e]
        float* ps = smem + 2048;   // 64 f32: pos
        for (int i = tid; i < P_ * H_; i += 512) hs[i] = h[(size_t)s * P_ * H_ + i];
        if (tid < 64) ps[tid] = pos[s * 64 + tid];
        __syncthreads();
        float wq0 = 0.f, wq1 = 0.f;
        for (int e = 0; e < E_; ++e) {
            float wv = W1[e * D1_ + d];
            wq0 += We[e] * wv;
            wq1 += We[E_ + e] * wv;
        }
        float w[P_];
#pragma unroll
        for (int j = 0; j < P_; ++j) w[j] = 0.f;
        const float4* h4 = (const float4*)hs;
        for (int e4 = 0; e4 < 16; ++e4) {
            const float c0 = W1[(E_ + e4 * 4 + 0) * D1_ + d];
            const float c1 = W1[(E_ + e4 * 4 + 1) * D1_ + d];
            const float c2 = W1[(E_ + e4 * 4 + 2) * D1_ + d];
            const float c3 = W1[(E_ + e4 * 4 + 3) * D1_ + d];
#pragma unroll
            for (int j = 0; j < P_; ++j) {
                float4 hv = h4[j * 16 + e4];
                w[j] += hv.x * c0 + hv.y * c1 + hv.z * c2 + hv.w * c3;
            }
        }
        float sw = 0.f, sww = 0.f, su = 0.f, suu = 0.f;
#pragma unroll
        for (int j = 0; j < P_; ++j) {
            float u = ps[2 * j] * wq0 + ps[2 * j + 1] * wq1;
            w[j] += u;
            sw += w[j]; sww += w[j] * w[j];
            su += u;    suu += u * u;
        }
        const float mw = sw * (1.f / P_), mu = su * (1.f / P_);
        const float var = (sww * (1.f / P_) - mw * mw) + (suu * (1.f / P_) - mu * mu);
        const float sc = rsqrtf(var + EPS_) * g1[d];
        const float bb = be1[d];
#pragma unroll
        for (int j = 0; j < P_; ++j) {
            float u = ps[2 * j] * wq0 + ps[2 * j + 1] * wq1;
            A[(size_t)(s * P_ + j) * D1_ + d] = (w[j] - mw) * sc + bb;
            Bv[(size_t)(s * P_ + j) * D1_ + d] = (u - mu) * sc;
        }
    } else {
        const int b2 = bid - S_;        // 0..127
        const int bi = b2 & 15;         // n tile (64)
        const int bj = b2 >> 4;         // k tile (64)
        const int tx = tid & 63, ty = tid >> 6;  // 64 x 8
        float (*tile)[65] = (float (*)[65])smem;
#pragma unroll
        for (int i = 0; i < 64; i += 8)
            tile[ty + i][tx] = W2[(size_t)(bj * 64 + ty + i) * D2_ + bi * 64 + tx];
        __syncthreads();
#pragma unroll
        for (int i = 0; i < 64; i += 8)
            w2t[(size_t)(bi * 64 + ty + i) * D1_ + bj * 64 + tx] = f2bf(tile[tx][ty + i]);
    }
}

// ---- fused GEMM: C[m,c] = sum_k bf16(relu(A[j,k]-B[kped,k])) * w2t[c,k]
// m = s*1024 + kped*32 + j. A-operand fragments computed in-register from the
// tiny L2-hot A/B arrays (x1 never materialized). LDS stages only w2t tiles.
// grid (8, 512): x = col tile -> XCD = colt (w2t strip L2-resident per XCD).
__global__ __launch_bounds__(256, 3)
void k_gemm(const float* __restrict__ A, const float* __restrict__ B,
            const u16* __restrict__ w2t,
            float* __restrict__ maxv, float* __restrict__ minv,
            float* __restrict__ psum, float* __restrict__ psumsq) {
    __shared__ u16 Bs[128 * 64];  // 16 KB
    const int colt = blockIdx.x;  // 0..7
    const int rowt = blockIdx.y;  // 0..511
    const int N0 = colt << 7;
    const int tid = threadIdx.x;
    const int wave = tid >> 6, lane = tid & 63;
    const int wm = wave >> 1, wn = wave & 1;
    const int quad = lane >> 4, l16 = lane & 15;
    const int lrow = lane >> 3, lchk = lane & 7;
    const int gchk = lchk ^ lrow;

    // A/B row pointers for this lane's 4 (j,k) fragment combos
    const int s = rowt >> 3;
    const int kb = ((rowt & 7) << 2) + (wm << 1);  // ped index within scene
    const float* Arow0 = A + ((size_t)(s * 32 + l16)) * D1_;
    const float* Arow1 = Arow0 + (size_t)16 * D1_;
    const float* Brow0 = B + ((size_t)(s * 32 + kb)) * D1_;
    const float* Brow1 = Brow0 + D1_;

    floatx4 acc[4][4] = {};

    for (int it = 0; it < 8; ++it) {
        const int k0 = it << 6;
        // stage w2t tile: 128 rows x 64 k, 4 loads per wave
#pragma unroll
        for (int t = 0; t < 4; ++t) {
            const int rbase = (wave << 5) + (t << 3);
            const u16* gb = w2t + (size_t)(N0 + rbase + lrow) * D1_ + (k0 + (gchk << 3));
            __builtin_amdgcn_global_load_lds(
                (const __attribute__((address_space(1))) void*)gb,
                (__attribute__((address_space(3))) void*)(Bs + (rbase << 6)), 16, 0, 0);
        }
        __syncthreads();
#pragma unroll
        for (int kk = 0; kk < 2; ++kk) {
            const int kc = k0 + (kk << 5) + (quad << 3);
            const float4 a0lo = *(const float4*)(Arow0 + kc);
            const float4 a0hi = *(const float4*)(Arow0 + kc + 4);
            const float4 a1lo = *(const float4*)(Arow1 + kc);
            const float4 a1hi = *(const float4*)(Arow1 + kc + 4);
            const float4 b0lo = *(const float4*)(Brow0 + kc);
            const float4 b0hi = *(const float4*)(Brow0 + kc + 4);
            const float4 b1lo = *(const float4*)(Brow1 + kc);
            const float4 b1hi = *(const float4*)(Brow1 + kc + 4);
            bf16x8 af[4], bfr[4];
            af[0] = frag_relu_diff(a0lo, a0hi, b0lo, b0hi);  // j=l16,    k=kb
            af[1] = frag_relu_diff(a1lo, a1hi, b0lo, b0hi);  // j=l16+16, k=kb
            af[2] = frag_relu_diff(a0lo, a0hi, b1lo, b1hi);  // j=l16,    k=kb+1
            af[3] = frag_relu_diff(a1lo, a1hi, b1lo, b1hi);  // j=l16+16, k=kb+1
#pragma unroll
            for (int tn = 0; tn < 4; ++tn) {
                const int row = (wn << 6) + (tn << 4) + l16;
                const int sc = ((kk << 2) + quad) ^ (row & 7);
                bfr[tn] = *(const bf16x8*)(Bs + (row << 6) + (sc << 3));
            }
#pragma unroll
            for (int tm = 0; tm < 4; ++tm)
#pragma unroll
                for (int tn = 0; tn < 4; ++tn)
                    acc[tm][tn] = __builtin_amdgcn_mfma_f32_16x16x32_bf16(
                        af[tm], bfr[tn], acc[tm][tn], 0, 0, 0);
        }
        __syncthreads();
    }

    // epilogue: rows of acc are m-tile rows; tm pairs (0,1)=ped kb, (2,3)=ped kb+1
    // (row = wm*64 + tm*16 + l16 -> j = (tm&1)*16+l16, ped = kb + (tm>>1))
    const int rb = rowt & 7;
#pragma unroll
    for (int tn = 0; tn < 4; ++tn) {
        const int col = N0 + (wn << 6) + (tn << 4) + l16;
        float wsum = 0.f, wsq = 0.f;
#pragma unroll
        for (int gp = 0; gp < 2; ++gp) {
            float vmax = -3.4e38f, vmin = 3.4e38f, vs = 0.f, vq = 0.f;
#pragma unroll
            for (int tm = gp * 2; tm < gp * 2 + 2; ++tm)
#pragma unroll
                for (int r = 0; r < 4; ++r) {
                    float v = acc[tm][tn][r];
                    vmax = fmaxf(vmax, v);
                    vmin = fminf(vmin, v);
                    vs += v;
                    vq += v * v;
                }
#pragma unroll
            for (int off = 16; off < 64; off <<= 1) {
                vmax = fmaxf(vmax, __shfl_xor(vmax, off));
                vmin = fminf(vmin, __shfl_xor(vmin, off));
                vs += __shfl_xor(vs, off);
                vq += __shfl_xor(vq, off);
            }
            if (quad == 0) {
                const int kg = s * 32 + kb + gp;  // global ped row 0..2047
                maxv[(size_t)kg * D2_ + col] = vmax;
                minv[(size_t)kg * D2_ + col] = vmin;
            }
            wsum += vs;
            wsq += vq;
        }
        if (quad == 0) {
            const int slot = (s << 4) + (rb << 1) + wm;  // 16 slots per scene
            psum[(size_t)slot * D2_ + col] = wsum;
            psumsq[(size_t)slot * D2_ + col] = wsq;
        }
    }
}

// ---- BN2 + relu on the j-maxed values ----
__global__ void k_final(const float* __restrict__ maxv, const float* __restrict__ minv,
                        const float* __restrict__ psum, const float* __restrict__ psumsq,
                        const float* __restrict__ g2, const float* __restrict__ be2,
                        float* __restrict__ out) {
    const int c = blockIdx.x * 256 + threadIdx.x;  // 0..1023
    const int s = blockIdx.y;
    float sm = 0.f, sq = 0.f;
#pragma unroll
    for (int t = 0; t < 16; ++t) {
        sm += psum[(size_t)(s * 16 + t) * D2_ + c];
        sq += psumsq[(size_t)(s * 16 + t) * D2_ + c];
    }
    const float mu = sm * (1.f / 1024.f);
    const float var = sq * (1.f / 1024.f) - mu * mu;
    const float inv = rsqrtf(var + EPS_);
    const float scale = g2[c] * inv;
    const float bb = be2[c];
    const float* src = (scale >= 0.f) ? maxv : minv;  // BN monotone direction
    for (int k = 0; k < 32; ++k) {
        const float v = src[(size_t)(s * 32 + k) * D2_ + c];
        out[(size_t)(s * 32 + k) * D2_ + c] = fmaxf((v - mu) * scale + bb, 0.f);
    }
}

extern "C" void kernel_launch(void* const* d_in, const int* in_sizes, int n_in,
                              void* d_out, int out_size, void* d_ws, size_t ws_size,
                              hipStream_t stream) {
    const float* h_states = (const float*)d_in[0];
    const float* end_pos = (const float*)d_in[2];
    const float* W_embed = (const float*)d_in[4];
    const float* W1 = (const float*)d_in[6];
    const float* g1 = (const float*)d_in[8];
    const float* be1 = (const float*)d_in[9];
    const float* W2 = (const float*)d_in[10];
    const float* g2 = (const float*)d_in[12];
    const float* be2 = (const float*)d_in[13];
    float* out = (float*)d_out;

    // workspace layout (~33 MiB)
    float* Abuf = (float*)d_ws;                // 1,048,576 f
    float* Bbuf = Abuf + 1048576;              // 1,048,576 f
    float* maxv = Bbuf + 1048576;              // 2,097,152 f
    float* minv = maxv + 2097152;              // 2,097,152 f
    float* psum = minv + 2097152;              // 1,048,576 f
    float* psumsq = psum + 1048576;            // 1,048,576 f
    u16* w2t = (u16*)(psumsq + 1048576);       // 524,288 u16

    k_prep<<<dim3(S_ + 128), dim3(512), 0, stream>>>(end_pos, h_states, W_embed, W1,
                                                     g1, be1, W2, Abuf, Bbuf, w2t);
    k_gemm<<<dim3(8, 512), dim3(256), 0, stream>>>(Abuf, Bbuf, w2t, maxv, minv, psum, psumsq);
    k_final<<<dim3(4, 64), dim3(256), 0, stream>>>(maxv, minv, psum, psumsq, g2, be2, out);
}

// Round 4
// 235.337 us; speedup vs baseline: 1.3747x; 1.3747x over previous
//
#include <hip/hip_runtime.h>
#include <hip/hip_bf16.h>

#define S_ 64
#define P_ 32
#define N_ 2048
#define H_ 64
#define E_ 64
#define D1_ 512
#define D2_ 1024
#define EPS_ 1e-5f

typedef unsigned short u16;
using bf16x8 = __attribute__((ext_vector_type(8))) __bf16;
using floatx4 = __attribute__((ext_vector_type(4))) float;

__device__ inline u16 f2bf(float x) {
    unsigned u = __float_as_uint(x);
    unsigned r = (u + 0x7fffu + ((u >> 16) & 1u)) >> 16;
    return (u16)r;
}
__device__ inline unsigned bf2pack(float lo, float hi) {
    return (unsigned)f2bf(lo) | ((unsigned)f2bf(hi) << 16);
}

// ---- fused prep: blocks 0..63 -> per-scene Weq+wu+BN1; blocks 64..191 -> W2 transpose ----
// A[n,d] = (w[n,d]-mean_w)*sc+be1 ; B[n,d] = (u[n,d]-mean_u)*sc   (per scene, per d)
__global__ __launch_bounds__(512)
void k_prep(const float* __restrict__ pos, const float* __restrict__ h,
            const float* __restrict__ We, const float* __restrict__ W1,
            const float* __restrict__ g1, const float* __restrict__ be1,
            const float* __restrict__ W2,
            float* __restrict__ A, float* __restrict__ Bv, u16* __restrict__ w2t) {
    __shared__ float smem[64 * 65];
    const int bid = blockIdx.x;
    const int tid = threadIdx.x;
    if (bid < S_) {
        const int s = bid;
        const int d = tid;  // 512 threads = 512 channels
        float* hs = smem;          // 2048 f32: h[j][e]
        float* ps = smem + 2048;   // 64 f32: pos
        for (int i = tid; i < P_ * H_; i += 512) hs[i] = h[(size_t)s * P_ * H_ + i];
        if (tid < 64) ps[tid] = pos[s * 64 + tid];
        __syncthreads();
        float wq0 = 0.f, wq1 = 0.f;
        for (int e = 0; e < E_; ++e) {
            float wv = W1[e * D1_ + d];
            wq0 += We[e] * wv;
            wq1 += We[E_ + e] * wv;
        }
        float w[P_];
#pragma unroll
        for (int j = 0; j < P_; ++j) w[j] = 0.f;
        const float4* h4 = (const float4*)hs;
        for (int e4 = 0; e4 < 16; ++e4) {
            const float c0 = W1[(E_ + e4 * 4 + 0) * D1_ + d];
            const float c1 = W1[(E_ + e4 * 4 + 1) * D1_ + d];
            const float c2 = W1[(E_ + e4 * 4 + 2) * D1_ + d];
            const float c3 = W1[(E_ + e4 * 4 + 3) * D1_ + d];
#pragma unroll
            for (int j = 0; j < P_; ++j) {
                float4 hv = h4[j * 16 + e4];
                w[j] += hv.x * c0 + hv.y * c1 + hv.z * c2 + hv.w * c3;
            }
        }
        float sw = 0.f, sww = 0.f, su = 0.f, suu = 0.f;
#pragma unroll
        for (int j = 0; j < P_; ++j) {
            float u = ps[2 * j] * wq0 + ps[2 * j + 1] * wq1;
            w[j] += u;
            sw += w[j]; sww += w[j] * w[j];
            su += u;    suu += u * u;
        }
        const float mw = sw * (1.f / P_), mu = su * (1.f / P_);
        const float var = (sww * (1.f / P_) - mw * mw) + (suu * (1.f / P_) - mu * mu);
        const float sc = rsqrtf(var + EPS_) * g1[d];
        const float bb = be1[d];
#pragma unroll
        for (int j = 0; j < P_; ++j) {
            float u = ps[2 * j] * wq0 + ps[2 * j + 1] * wq1;
            A[(size_t)(s * P_ + j) * D1_ + d] = (w[j] - mw) * sc + bb;
            Bv[(size_t)(s * P_ + j) * D1_ + d] = (u - mu) * sc;
        }
    } else {
        const int b2 = bid - S_;        // 0..127
        const int bi = b2 & 15;         // n tile (64)
        const int bj = b2 >> 4;         // k tile (64)
        const int tx = tid & 63, ty = tid >> 6;  // 64 x 8
        float (*tile)[65] = (float (*)[65])smem;
#pragma unroll
        for (int i = 0; i < 64; i += 8)
            tile[ty + i][tx] = W2[(size_t)(bj * 64 + ty + i) * D2_ + bi * 64 + tx];
        __syncthreads();
#pragma unroll
        for (int i = 0; i < 64; i += 8)
            w2t[(size_t)(bi * 64 + ty + i) * D1_ + bj * 64 + tx] = f2bf(tile[tx][ty + i]);
    }
}

// ---- fused GEMM: one block per 64-row strip (2 peds x 32 j), all 1024 cols ----
// Stage x1 strip bf16 into LDS once (coalesced), loop 8 col-tiles of 128,
// staging w2t tiles via global_load_lds. x1 never touches global memory.
__global__ __launch_bounds__(256, 2)
void k_gemm(const float* __restrict__ A, const float* __restrict__ B,
            const u16* __restrict__ w2t,
            float* __restrict__ maxv, float* __restrict__ minv,
            float* __restrict__ psum, float* __restrict__ psumsq) {
    __shared__ u16 Xs[64 * 512];   // 64 KB: x1 strip, chunk-swizzled
    __shared__ u16 Ws[128 * 64];   // 16 KB: w2t tile
    const int b = blockIdx.x;      // 0..1023
    const int s = b >> 4, rb = b & 15;
    const int kb0 = rb << 1;       // first ped of strip
    const int tid = threadIdx.x;
    const int wave = tid >> 6, lane = tid & 63;
    const int quad = lane >> 4, l16 = lane & 15;
    const int lrow = lane >> 3, lchk = lane & 7;
    const int gchk = lchk ^ lrow;

    // ---- stage x1 strip: row r (0..63) = ped (r>>5), j (r&31); 64 chunks of 8 ----
    {
        const int c = tid & 63;    // k-chunk
        const int rr = tid >> 6;   // 0..3
#pragma unroll
        for (int t = 0; t < 16; ++t) {
            const int r = (t << 2) + rr;
            const int j = r & 31;
            const int kp = kb0 + (r >> 5);
            const float4* Af = (const float4*)(A + ((size_t)(s * 32 + j) << 9) + (c << 3));
            const float4* Bf = (const float4*)(B + ((size_t)(s * 32 + kp) << 9) + (c << 3));
            const float4 alo = Af[0], ahi = Af[1];
            const float4 blo = Bf[0], bhi = Bf[1];
            uint4 o;
            o.x = bf2pack(fmaxf(alo.x - blo.x, 0.f), fmaxf(alo.y - blo.y, 0.f));
            o.y = bf2pack(fmaxf(alo.z - blo.z, 0.f), fmaxf(alo.w - blo.w, 0.f));
            o.z = bf2pack(fmaxf(ahi.x - bhi.x, 0.f), fmaxf(ahi.y - bhi.y, 0.f));
            o.w = bf2pack(fmaxf(ahi.z - bhi.z, 0.f), fmaxf(ahi.w - bhi.w, 0.f));
            const int p = (c & ~7) | ((c ^ r) & 7);  // bank swizzle
            *(uint4*)(Xs + (r << 9) + (p << 3)) = o;
        }
    }
    __syncthreads();

    for (int ct = 0; ct < 8; ++ct) {
        const int N0 = ct << 7;
        floatx4 acc[4][2] = {};
        for (int it = 0; it < 8; ++it) {
            const int k0 = it << 6;
#pragma unroll
            for (int t = 0; t < 4; ++t) {
                const int rbase = (wave << 5) + (t << 3);
                const u16* gb = w2t + (size_t)(N0 + rbase + lrow) * D1_ + (k0 + (gchk << 3));
                __builtin_amdgcn_global_load_lds(
                    (const __attribute__((address_space(1))) void*)gb,
                    (__attribute__((address_space(3))) void*)(Ws + (rbase << 6)), 16, 0, 0);
            }
            __syncthreads();
#pragma unroll
            for (int kk = 0; kk < 2; ++kk) {
                const int ck = (it << 3) + (kk << 2) + quad;  // global k-chunk 0..63
                bf16x8 af[4], wf[2];
#pragma unroll
                for (int tm = 0; tm < 4; ++tm) {
                    const int row = (tm << 4) + l16;
                    const int p = (ck & ~7) | ((ck ^ row) & 7);
                    af[tm] = *(const bf16x8*)(Xs + (row << 9) + (p << 3));
                }
#pragma unroll
                for (int tn = 0; tn < 2; ++tn) {
                    const int wrow = (wave << 5) + (tn << 4) + l16;
                    const int sc = ((kk << 2) + quad) ^ (wrow & 7);
                    wf[tn] = *(const bf16x8*)(Ws + (wrow << 6) + (sc << 3));
                }
#pragma unroll
                for (int tm = 0; tm < 4; ++tm)
#pragma unroll
                    for (int tn = 0; tn < 2; ++tn)
                        acc[tm][tn] = __builtin_amdgcn_mfma_f32_16x16x32_bf16(
                            af[tm], wf[tn], acc[tm][tn], 0, 0, 0);
            }
            __syncthreads();
        }
        // ---- epilogue for this col tile ----
        // acc row local = tm*16 + quad*4 + r; ped = (local>=32), j = local&31
#pragma unroll
        for (int tn = 0; tn < 2; ++tn) {
            const int col = N0 + (wave << 5) + (tn << 4) + l16;
            float wsum = 0.f, wsq = 0.f;
#pragma unroll
            for (int gp = 0; gp < 2; ++gp) {
                float vmax = -3.4e38f, vmin = 3.4e38f, vs = 0.f, vq = 0.f;
#pragma unroll
                for (int tm = gp * 2; tm < gp * 2 + 2; ++tm)
#pragma unroll
                    for (int r = 0; r < 4; ++r) {
                        float v = acc[tm][tn][r];
                        vmax = fmaxf(vmax, v);
                        vmin = fminf(vmin, v);
                        vs += v;
                        vq += v * v;
                    }
#pragma unroll
                for (int off = 16; off < 64; off <<= 1) {
                    vmax = fmaxf(vmax, __shfl_xor(vmax, off));
                    vmin = fminf(vmin, __shfl_xor(vmin, off));
                    vs += __shfl_xor(vs, off);
                    vq += __shfl_xor(vq, off);
                }
                if (quad == 0) {
                    const int kg = s * 32 + kb0 + gp;  // global ped row
                    maxv[(size_t)kg * D2_ + col] = vmax;
                    minv[(size_t)kg * D2_ + col] = vmin;
                }
                wsum += vs;
                wsq += vq;
            }
            if (quad == 0) {
                const int slot = (s << 4) + rb;  // 16 slots per scene
                psum[(size_t)slot * D2_ + col] = wsum;
                psumsq[(size_t)slot * D2_ + col] = wsq;
            }
        }
    }
}

// ---- BN2 + relu on the j-maxed values ----
__global__ void k_final(const float* __restrict__ maxv, const float* __restrict__ minv,
                        const float* __restrict__ psum, const float* __restrict__ psumsq,
                        const float* __restrict__ g2, const float* __restrict__ be2,
                        float* __restrict__ out) {
    const int c = blockIdx.x * 256 + threadIdx.x;  // 0..1023
    const int s = blockIdx.y;
    float sm = 0.f, sq = 0.f;
#pragma unroll
    for (int t = 0; t < 16; ++t) {
        sm += psum[(size_t)(s * 16 + t) * D2_ + c];
        sq += psumsq[(size_t)(s * 16 + t) * D2_ + c];
    }
    const float mu = sm * (1.f / 1024.f);
    const float var = sq * (1.f / 1024.f) - mu * mu;
    const float inv = rsqrtf(var + EPS_);
    const float scale = g2[c] * inv;
    const float bb = be2[c];
    const float* src = (scale >= 0.f) ? maxv : minv;  // BN monotone direction
    for (int k = 0; k < 32; ++k) {
        const float v = src[(size_t)(s * 32 + k) * D2_ + c];
        out[(size_t)(s * 32 + k) * D2_ + c] = fmaxf((v - mu) * scale + bb, 0.f);
    }
}

extern "C" void kernel_launch(void* const* d_in, const int* in_sizes, int n_in,
                              void* d_out, int out_size, void* d_ws, size_t ws_size,
                              hipStream_t stream) {
    const float* h_states = (const float*)d_in[0];
    const float* end_pos = (const float*)d_in[2];
    const float* W_embed = (const float*)d_in[4];
    const float* W1 = (const float*)d_in[6];
    const float* g1 = (const float*)d_in[8];
    const float* be1 = (const float*)d_in[9];
    const float* W2 = (const float*)d_in[10];
    const float* g2 = (const float*)d_in[12];
    const float* be2 = (const float*)d_in[13];
    float* out = (float*)d_out;

    // workspace layout (~33 MiB)
    float* Abuf = (float*)d_ws;                // 1,048,576 f
    float* Bbuf = Abuf + 1048576;              // 1,048,576 f
    float* maxv = Bbuf + 1048576;              // 2,097,152 f
    float* minv = maxv + 2097152;              // 2,097,152 f
    float* psum = minv + 2097152;              // 1,048,576 f
    float* psumsq = psum + 1048576;            // 1,048,576 f
    u16* w2t = (u16*)(psumsq + 1048576);       // 524,288 u16

    k_prep<<<dim3(S_ + 128), dim3(512), 0, stream>>>(end_pos, h_states, W_embed, W1,
                                                     g1, be1, W2, Abuf, Bbuf, w2t);
    k_gemm<<<dim3(1024), dim3(256), 0, stream>>>(Abuf, Bbuf, w2t, maxv, minv, psum, psumsq);
    k_final<<<dim3(4, 64), dim3(256), 0, stream>>>(maxv, minv, psum, psumsq, g2, be2, out);
}

// Round 5
// 199.050 us; speedup vs baseline: 1.6254x; 1.1823x over previous
//
#include <hip/hip_runtime.h>
#include <hip/hip_bf16.h>

#define S_ 64
#define P_ 32
#define N_ 2048
#define H_ 64
#define E_ 64
#define D1_ 512
#define D2_ 1024
#define EPS_ 1e-5f

typedef unsigned short u16;
using bf16x8 = __attribute__((ext_vector_type(8))) __bf16;
using floatx4 = __attribute__((ext_vector_type(4))) float;

__device__ inline u16 f2bf(float x) {
    unsigned u = __float_as_uint(x);
    unsigned r = (u + 0x7fffu + ((u >> 16) & 1u)) >> 16;
    return (u16)r;
}
__device__ inline unsigned bf2pack(float lo, float hi) {
    return (unsigned)f2bf(lo) | ((unsigned)f2bf(hi) << 16);
}

// ---- fused prep: blocks 0..63 -> per-scene Weq+wu+BN1; blocks 64..191 -> W2 transpose ----
__global__ __launch_bounds__(512)
void k_prep(const float* __restrict__ pos, const float* __restrict__ h,
            const float* __restrict__ We, const float* __restrict__ W1,
            const float* __restrict__ g1, const float* __restrict__ be1,
            const float* __restrict__ W2,
            float* __restrict__ A, float* __restrict__ Bv, u16* __restrict__ w2t) {
    __shared__ float smem[64 * 65];
    const int bid = blockIdx.x;
    const int tid = threadIdx.x;
    if (bid < S_) {
        const int s = bid;
        const int d = tid;  // 512 threads = 512 channels
        float* hs = smem;          // 2048 f32: h[j][e]
        float* ps = smem + 2048;   // 64 f32: pos
        for (int i = tid; i < P_ * H_; i += 512) hs[i] = h[(size_t)s * P_ * H_ + i];
        if (tid < 64) ps[tid] = pos[s * 64 + tid];
        __syncthreads();
        float wq0 = 0.f, wq1 = 0.f;
        for (int e = 0; e < E_; ++e) {
            float wv = W1[e * D1_ + d];
            wq0 += We[e] * wv;
            wq1 += We[E_ + e] * wv;
        }
        float w[P_];
#pragma unroll
        for (int j = 0; j < P_; ++j) w[j] = 0.f;
        const float4* h4 = (const float4*)hs;
        for (int e4 = 0; e4 < 16; ++e4) {
            const float c0 = W1[(E_ + e4 * 4 + 0) * D1_ + d];
            const float c1 = W1[(E_ + e4 * 4 + 1) * D1_ + d];
            const float c2 = W1[(E_ + e4 * 4 + 2) * D1_ + d];
            const float c3 = W1[(E_ + e4 * 4 + 3) * D1_ + d];
#pragma unroll
            for (int j = 0; j < P_; ++j) {
                float4 hv = h4[j * 16 + e4];
                w[j] += hv.x * c0 + hv.y * c1 + hv.z * c2 + hv.w * c3;
            }
        }
        float sw = 0.f, sww = 0.f, su = 0.f, suu = 0.f;
#pragma unroll
        for (int j = 0; j < P_; ++j) {
            float u = ps[2 * j] * wq0 + ps[2 * j + 1] * wq1;
            w[j] += u;
            sw += w[j]; sww += w[j] * w[j];
            su += u;    suu += u * u;
        }
        const float mw = sw * (1.f / P_), mu = su * (1.f / P_);
        const float var = (sww * (1.f / P_) - mw * mw) + (suu * (1.f / P_) - mu * mu);
        const float sc = rsqrtf(var + EPS_) * g1[d];
        const float bb = be1[d];
#pragma unroll
        for (int j = 0; j < P_; ++j) {
            float u = ps[2 * j] * wq0 + ps[2 * j + 1] * wq1;
            A[(size_t)(s * P_ + j) * D1_ + d] = (w[j] - mw) * sc + bb;
            Bv[(size_t)(s * P_ + j) * D1_ + d] = (u - mu) * sc;
        }
    } else {
        const int b2 = bid - S_;        // 0..127
        const int bi = b2 & 15;         // n tile (64)
        const int bj = b2 >> 4;         // k tile (64)
        const int tx = tid & 63, ty = tid >> 6;  // 64 x 8
        float (*tile)[65] = (float (*)[65])smem;
#pragma unroll
        for (int i = 0; i < 64; i += 8)
            tile[ty + i][tx] = W2[(size_t)(bj * 64 + ty + i) * D2_ + bi * 64 + tx];
        __syncthreads();
#pragma unroll
        for (int i = 0; i < 64; i += 8)
            w2t[(size_t)(bi * 64 + ty + i) * D1_ + bj * 64 + tx] = f2bf(tile[tx][ty + i]);
    }
}

// ---- fused GEMM: block = 128 rows (4 peds x 32 j) x 256 cols; x1 built in LDS.
// Per K-slice(64): stage As (16 KB per-lane relu-diff, R1 stride-64 XOR layout)
// + Ws (32 KB global_load_lds), then 64 MFMA/wave (tm4 x tn8). 16 barriers.
__global__ __launch_bounds__(256, 2)
void k_gemm(const float* __restrict__ A, const float* __restrict__ B,
            const u16* __restrict__ w2t,
            float* __restrict__ maxv, float* __restrict__ minv,
            float* __restrict__ psum, float* __restrict__ psumsq) {
    __shared__ u16 As[128 * 64];   // 16 KB: x1 K-slice
    __shared__ u16 Ws[256 * 64];   // 32 KB: w2t K-slice
    const int cs = blockIdx.x;     // col split 0..3
    const int mt = blockIdx.y;     // M tile 0..511
    const int s = mt >> 3, rb = mt & 7;
    const int pedb = rb << 2;      // first ped of the 128-row tile
    const int N0 = cs << 8;
    const int tid = threadIdx.x;
    const int wave = tid >> 6, lane = tid & 63;
    const int wm = wave >> 1, wn = wave & 1;
    const int quad = lane >> 4, l16 = lane & 15;
    const int lrow = lane >> 3, lchk = lane & 7;
    const int gchk = lchk ^ lrow;

    // staging thread mapping for As: j = tid>>3, chunk c = tid&7
    const int sj = tid >> 3, sc8 = tid & 7;
    const float* Aj = A + ((size_t)(s * 32 + sj) << 9) + (sc8 << 3);
    const float* Bp = B + ((size_t)(s * 32 + pedb) << 9) + (sc8 << 3);
    const int swz = (sc8 ^ (sj & 7)) << 3;

    floatx4 acc[4][8] = {};

    for (int it = 0; it < 8; ++it) {
        const int k0 = it << 6;
        // ---- stage Ws: 256 rows x 64 k via global_load_lds ----
#pragma unroll
        for (int t = 0; t < 8; ++t) {
            const int rbase = (wave << 6) + (t << 3);
            const u16* gb = w2t + (size_t)(N0 + rbase + lrow) * D1_ + (k0 + (gchk << 3));
            __builtin_amdgcn_global_load_lds(
                (const __attribute__((address_space(1))) void*)gb,
                (__attribute__((address_space(3))) void*)(Ws + (rbase << 6)), 16, 0, 0);
        }
        // ---- stage As: 128 rows (4 peds x 32 j) x 64 k, per-lane relu-diff ----
#pragma unroll
        for (int p = 0; p < 4; ++p) {
            const int r = (p << 5) + sj;
            const float4 alo = *(const float4*)(Aj + k0);
            const float4 ahi = *(const float4*)(Aj + k0 + 4);
            const float4 blo = *(const float4*)(Bp + ((size_t)p << 9) + k0);
            const float4 bhi = *(const float4*)(Bp + ((size_t)p << 9) + k0 + 4);
            uint4 o;
            o.x = bf2pack(fmaxf(alo.x - blo.x, 0.f), fmaxf(alo.y - blo.y, 0.f));
            o.y = bf2pack(fmaxf(alo.z - blo.z, 0.f), fmaxf(alo.w - blo.w, 0.f));
            o.z = bf2pack(fmaxf(ahi.x - bhi.x, 0.f), fmaxf(ahi.y - bhi.y, 0.f));
            o.w = bf2pack(fmaxf(ahi.z - bhi.z, 0.f), fmaxf(ahi.w - bhi.w, 0.f));
            *(uint4*)(As + (r << 6) + swz) = o;
        }
        __syncthreads();
        // ---- compute: 2 kk x (af4 x wf8) = 64 MFMA per wave ----
#pragma unroll
        for (int kk = 0; kk < 2; ++kk) {
            const int ck = (kk << 2) + quad;
            const int po = (ck ^ (l16 & 7)) << 3;  // row&7 == l16&7 for all frags
            bf16x8 af[4], wf[8];
#pragma unroll
            for (int tm = 0; tm < 4; ++tm) {
                const int row = (wm << 6) + (tm << 4) + l16;
                af[tm] = *(const bf16x8*)(As + (row << 6) + po);
            }
#pragma unroll
            for (int tn = 0; tn < 8; ++tn) {
                const int row = (wn << 7) + (tn << 4) + l16;
                wf[tn] = *(const bf16x8*)(Ws + (row << 6) + po);
            }
#pragma unroll
            for (int tm = 0; tm < 4; ++tm)
#pragma unroll
                for (int tn = 0; tn < 8; ++tn)
                    acc[tm][tn] = __builtin_amdgcn_mfma_f32_16x16x32_bf16(
                        af[tm], wf[tn], acc[tm][tn], 0, 0, 0);
        }
        __syncthreads();
    }

    // ---- epilogue ----
    // acc row_local = wm*64 + tm*16 + quad*4 + r; ped = pedb + wm*2 + (tm>>1)
#pragma unroll
    for (int tn = 0; tn < 8; ++tn) {
        const int col = N0 + (wn << 7) + (tn << 4) + l16;
        float wsum = 0.f, wsq = 0.f;
#pragma unroll
        for (int gp = 0; gp < 2; ++gp) {
            float vmax = -3.4e38f, vmin = 3.4e38f, vs = 0.f, vq = 0.f;
#pragma unroll
            for (int tm = gp * 2; tm < gp * 2 + 2; ++tm)
#pragma unroll
                for (int r = 0; r < 4; ++r) {
                    float v = acc[tm][tn][r];
                    vmax = fmaxf(vmax, v);
                    vmin = fminf(vmin, v);
                    vs += v;
                    vq += v * v;
                }
#pragma unroll
            for (int off = 16; off < 64; off <<= 1) {
                vmax = fmaxf(vmax, __shfl_xor(vmax, off));
                vmin = fminf(vmin, __shfl_xor(vmin, off));
                vs += __shfl_xor(vs, off);
                vq += __shfl_xor(vq, off);
            }
            if (quad == 0) {
                const int kg = s * 32 + pedb + (wm << 1) + gp;  // global ped row
                maxv[(size_t)kg * D2_ + col] = vmax;
                minv[(size_t)kg * D2_ + col] = vmin;
            }
            wsum += vs;
            wsq += vq;
        }
        if (quad == 0) {
            const int slot = (s << 4) + (rb << 1) + wm;  // 16 slots per scene
            psum[(size_t)slot * D2_ + col] = wsum;
            psumsq[(size_t)slot * D2_ + col] = wsq;
        }
    }
}

// ---- BN2 + relu on the j-maxed values ----
__global__ void k_final(const float* __restrict__ maxv, const float* __restrict__ minv,
                        const float* __restrict__ psum, const float* __restrict__ psumsq,
                        const float* __restrict__ g2, const float* __restrict__ be2,
                        float* __restrict__ out) {
    const int c = blockIdx.x * 256 + threadIdx.x;  // 0..1023
    const int s = blockIdx.y;
    float sm = 0.f, sq = 0.f;
#pragma unroll
    for (int t = 0; t < 16; ++t) {
        sm += psum[(size_t)(s * 16 + t) * D2_ + c];
        sq += psumsq[(size_t)(s * 16 + t) * D2_ + c];
    }
    const float mu = sm * (1.f / 1024.f);
    const float var = sq * (1.f / 1024.f) - mu * mu;
    const float inv = rsqrtf(var + EPS_);
    const float scale = g2[c] * inv;
    const float bb = be2[c];
    const float* src = (scale >= 0.f) ? maxv : minv;  // BN monotone direction
    for (int k = 0; k < 32; ++k) {
        const float v = src[(size_t)(s * 32 + k) * D2_ + c];
        out[(size_t)(s * 32 + k) * D2_ + c] = fmaxf((v - mu) * scale + bb, 0.f);
    }
}

extern "C" void kernel_launch(void* const* d_in, const int* in_sizes, int n_in,
                              void* d_out, int out_size, void* d_ws, size_t ws_size,
                              hipStream_t stream) {
    const float* h_states = (const float*)d_in[0];
    const float* end_pos = (const float*)d_in[2];
    const float* W_embed = (const float*)d_in[4];
    const float* W1 = (const float*)d_in[6];
    const float* g1 = (const float*)d_in[8];
    const float* be1 = (const float*)d_in[9];
    const float* W2 = (const float*)d_in[10];
    const float* g2 = (const float*)d_in[12];
    const float* be2 = (const float*)d_in[13];
    float* out = (float*)d_out;

    // workspace layout (~33 MiB)
    float* Abuf = (float*)d_ws;                // 1,048,576 f
    float* Bbuf = Abuf + 1048576;              // 1,048,576 f
    float* maxv = Bbuf + 1048576;              // 2,097,152 f
    float* minv = maxv + 2097152;              // 2,097,152 f
    float* psum = minv + 2097152;              // 1,048,576 f
    float* psumsq = psum + 1048576;            // 1,048,576 f
    u16* w2t = (u16*)(psumsq + 1048576);       // 524,288 u16

    k_prep<<<dim3(S_ + 128), dim3(512), 0, stream>>>(end_pos, h_states, W_embed, W1,
                                                     g1, be1, W2, Abuf, Bbuf, w2t);
    k_gemm<<<dim3(4, 512), dim3(256), 0, stream>>>(Abuf, Bbuf, w2t, maxv, minv, psum, psumsq);
    k_final<<<dim3(4, 64), dim3(256), 0, stream>>>(maxv, minv, psum, psumsq, g2, be2, out);
}